// Round 9
// baseline (1215.810 us; speedup 1.0000x reference)
//
#include <hip/hip_runtime.h>
#include <hip/hip_bf16.h>

// LSTM cell fused kernel for MI355X (gfx950) — round 9: 2-blocks-per-CU.
// stacked = [x|prevh] @ [Wx;Wh] + bx -> gates -> nexth, nextc
// GEMM: M=8192, N=4096 (4 gates x 1024 states), K=2048, bf16 16x16x32 MFMA.
//
// Thesis: rounds 1-8 all ran 1 resident block/CU (128KB LDS) -> 2 waves/SIMD;
// every barrier/vmcnt stall idled the CU. This round: BK=32, 2-slot dbuf =
// 64KB LDS + __launch_bounds__(512,4) -> 2 resident blocks (4 waves/SIMD);
// block X's stalls are covered by block Y's MFMAs (m114 co-scheduling).
// All 512 blocks resident simultaneously -> no sequential block generations.
//
// Registers at 4 waves/SIMD: acc 8x4 f32x4 = 128 AGPR (=512/4 exactly);
// frags af[8]+bf[4] = 48 VGPR + addressing ~60 -> <=128 VGPR.
//
// Per K-tile t (64 tiles of BK=32):
//   issue 12 ds_read_b128 (bf g0-3, af m0-3 | af m4-7)
//   issue S(t+1): 4 gload_lds (A 2 rounds + B 2 rounds)
//   lgkm(4) -> first 8 reads done; 16 MFMA (m0-3 x g0-3)
//   lgkm(0) -> rest;               16 MFMA (m4-7 x g0-3)
//   vmcnt(0) [loads issued a full tile ago] ; barrier
// WAR: S(t+1) writes slot (t+1)&1 != t&1; old content (t-1) fully read
// before end-barrier(t-1). RAW: slot t staged at t-1 top, confirmed by
// vmcnt(0)+barrier at t-1 end. Safe.
//
// LDS swizzle (64B rows, 4 x 16B slots): dest[row][slot] holds logical
// [row][slot ^ ((row>>2)&3)]. Staging: linear gload_lds dest + source col
// = (slot ^ ((row>>2)&3))*8 elems. Read: slot' = (l>>4) ^ ((l>>2)&3).
// Per-wave b128: 8 lanes per 16B bank-group, perfectly even -> 0 conflicts.
//
// Gate fusion (verified r1-r7): Wt permuted n' = (s>>4)*64 + g*16 + (s&15);
// each wave's 64 n'-cols = 16 states x 4 gates -> lane-local epilogue.
//
// ws: A_bf16 [8192][2048] (32MB) | Wt bf16 [4096 perm][2048] (16MB)

#define BATCH   8192
#define SDIM    1024
#define KDIM    2048
#define NT      64      // K-tiles of 32

typedef __attribute__((ext_vector_type(8))) short s16x8;
typedef __attribute__((ext_vector_type(4))) float f32x4;

__device__ __forceinline__ void gload16(const void* g, void* l) {
    __builtin_amdgcn_global_load_lds((const __attribute__((address_space(1))) void*)g,
                                     (__attribute__((address_space(3))) void*)l,
                                     16, 0, 0);
}

__device__ __forceinline__ float fast_sigmoid(float x) {
    return 1.0f / (1.0f + __expf(-x));
}
__device__ __forceinline__ float fast_tanh(float v) {
    float a = fabsf(v);
    float e = __expf(-2.0f * a);
    float t = (1.0f - e) / (1.0f + e);
    return copysignf(t, v);
}

// ---------------- conversion: A = [x | prevh] -> bf16 [8192][2048] ----------
__global__ void convA(const float* __restrict__ x, const float* __restrict__ h,
                      __hip_bfloat16* __restrict__ A) {
    int t = blockIdx.x * blockDim.x + threadIdx.x;
    int e = t << 3;
    int b = e >> 11;
    int k = e & 2047;
    const float* src = (k < 1024) ? (x + (size_t)b * 1024 + k)
                                  : (h + (size_t)b * 1024 + (k - 1024));
    float4 v0 = *(const float4*)(src);
    float4 v1 = *(const float4*)(src + 4);
    union { __hip_bfloat16 b[8]; s16x8 v; } u;
    u.b[0] = __float2bfloat16(v0.x); u.b[1] = __float2bfloat16(v0.y);
    u.b[2] = __float2bfloat16(v0.z); u.b[3] = __float2bfloat16(v0.w);
    u.b[4] = __float2bfloat16(v1.x); u.b[5] = __float2bfloat16(v1.y);
    u.b[6] = __float2bfloat16(v1.z); u.b[7] = __float2bfloat16(v1.w);
    *(s16x8*)(A + e) = u.v;
}

// ---- conversion + transpose + gate-permute: Wt[n'][k] = W[k][n] -----------
// n = gate*1024 + s  ->  n' = (s>>4)*64 + gate*16 + (s&15)
__global__ void convW(const float* __restrict__ Wx, const float* __restrict__ Wh,
                      __hip_bfloat16* __restrict__ Wt) {
    __shared__ float tile[32][33];
    int k0 = blockIdx.x * 32;
    int n0 = blockIdx.y * 32;
    int tx = threadIdx.x;
    int ty = threadIdx.y;
#pragma unroll
    for (int j = 0; j < 4; ++j) {
        int k = k0 + ty + j * 8;
        int n = n0 + tx;
        float v = (k < 1024) ? Wx[(size_t)k * 4096 + n]
                             : Wh[(size_t)(k - 1024) * 4096 + n];
        tile[ty + j * 8][tx] = v;
    }
    __syncthreads();
#pragma unroll
    for (int j = 0; j < 4; ++j) {
        int n = n0 + ty + j * 8;
        int k = k0 + tx;
        int np = ((n & 1023) >> 4) * 64 + (n >> 10) * 16 + (n & 15);
        Wt[(size_t)np * 2048 + k] = __float2bfloat16(tile[tx][ty + j * 8]);
    }
}

// ---------------- fused GEMM + gates ----------------------------------------
__global__ __launch_bounds__(512, 4) void lstm_gemm(
    const __hip_bfloat16* __restrict__ A,    // [8192][2048]
    const __hip_bfloat16* __restrict__ Wt,   // [4096 perm][2048]
    const float* __restrict__ bx,            // [4096]
    const float* __restrict__ prevc,         // [8192][1024]
    float* __restrict__ outh,
    float* __restrict__ outc)
{
    // A slots: [0,16K),[16K,32K); B slots: [32K,48K),[48K,64K).
    __shared__ __align__(16) char lds[65536];

    const int tid  = threadIdx.x;
    const int lane = tid & 63;
    const int w    = tid >> 6;   // 0..7
    const int wr   = w >> 2;     // 0..1  A-half (128 rows)
    const int wc   = w & 3;      // 0..3  N quarter (64 n'-cols)
    const int l15  = lane & 15;

    // XCD chunking (FETCH-verified): 8 chunks of 8Mt x 8Nt.
    const int bid = blockIdx.x;
    const int xcd = bid & 7, jj = bid >> 3;
    const int mt = (xcd >> 1) * 8 + (jj & 7);     // 0..31
    const int nt = (xcd & 1) * 8 + (jj >> 3);     // 0..15
    const int m0 = mt * 256, n0 = nt * 256, S0 = nt * 64;

    // staging: linear gload_lds dest; inverse-swizzled source column.
    // thread covers dest row w*16+(lane>>2) (+128/round), slot lane&3.
    const int scol = (((lane & 3) ^ ((lane >> 4) & 3)) << 3);   // elems
    const __hip_bfloat16* Ag = A  + (size_t)m0 * KDIM;
    const __hip_bfloat16* Bg = Wt + (size_t)n0 * KDIM;

    auto SA = [&](int tt) {
        char* dst = lds + (tt & 1) * 16384 + w * 1024;
        const __hip_bfloat16* src =
            Ag + (size_t)(w * 16 + (lane >> 2)) * KDIM + tt * 32 + scol;
        gload16(src, dst);
        gload16(src + (size_t)128 * KDIM, dst + 8192);
    };
    auto SB = [&](int tt) {
        char* dst = lds + 32768 + (tt & 1) * 16384 + w * 1024;
        const __hip_bfloat16* src =
            Bg + (size_t)(w * 16 + (lane >> 2)) * KDIM + tt * 32 + scol;
        gload16(src, dst);
        gload16(src + (size_t)128 * KDIM, dst + 8192);
    };

    f32x4 acc[8][4];
#pragma unroll
    for (int m = 0; m < 8; ++m)
#pragma unroll
        for (int g = 0; g < 4; ++g)
            acc[m][g] = (f32x4)0.0f;

    // prologue
    SA(0); SB(0);
    asm volatile("s_waitcnt vmcnt(0)" ::: "memory");
    __builtin_amdgcn_s_barrier();
    __builtin_amdgcn_sched_barrier(0);

    // read-side swizzle: slot' = (l>>4) ^ ((l>>2)&3); row-independent.
    const int swz = (((lane >> 4) ^ ((lane >> 2) & 3)) << 4);
    const int abase = wr * 128 + l15;   // + m*16, row units
    const int bbase = wc * 64  + l15;   // + g*16

    s16x8 af[8], bf[4];

    for (int t = 0; t < NT; ++t) {
        const char* as = lds + (t & 1) * 16384;
        const char* bs = lds + 32768 + (t & 1) * 16384;

        // ---- issue all 12 frag reads ----
#pragma unroll
        for (int g = 0; g < 4; ++g)
            bf[g] = *(const s16x8*)(bs + (bbase + g * 16) * 64 + swz);
#pragma unroll
        for (int m = 0; m < 4; ++m)
            af[m] = *(const s16x8*)(as + (abase + m * 16) * 64 + swz);
#pragma unroll
        for (int m = 4; m < 8; ++m)
            af[m] = *(const s16x8*)(as + (abase + m * 16) * 64 + swz);

        // ---- issue next-tile staging (4 gloads) ----
        if (t + 1 < NT) { SA(t + 1); SB(t + 1); }

        asm volatile("s_waitcnt lgkmcnt(4)" ::: "memory");   // bf + af0-3 done
        __builtin_amdgcn_sched_barrier(0);
        __builtin_amdgcn_s_setprio(1);
#pragma unroll
        for (int m = 0; m < 4; ++m)
#pragma unroll
            for (int g = 0; g < 4; ++g)
                acc[m][g] = __builtin_amdgcn_mfma_f32_16x16x32_bf16(
                    af[m], bf[g], acc[m][g], 0, 0, 0);
        __builtin_amdgcn_s_setprio(0);

        asm volatile("s_waitcnt lgkmcnt(0)" ::: "memory");   // af4-7 done
        __builtin_amdgcn_sched_barrier(0);
        __builtin_amdgcn_s_setprio(1);
#pragma unroll
        for (int m = 4; m < 8; ++m)
#pragma unroll
            for (int g = 0; g < 4; ++g)
                acc[m][g] = __builtin_amdgcn_mfma_f32_16x16x32_bf16(
                    af[m], bf[g], acc[m][g], 0, 0, 0);
        __builtin_amdgcn_s_setprio(0);

        // staged loads issued ~a full tile ago; other resident block covers
        // the drain+barrier (the point of this round).
        asm volatile("s_waitcnt vmcnt(0)" ::: "memory");
        __builtin_amdgcn_s_barrier();
        __builtin_amdgcn_sched_barrier(0);
    }

    // ---- fused epilogue: 4 gates lane-local ----
    const int st  = S0 + wc * 16 + l15;
    const float b_i = bx[st];
    const float b_f = bx[1024 + st];
    const float b_o = bx[2048 + st];
    const float b_g = bx[3072 + st];
    const int rbase = m0 + wr * 128 + (lane >> 4) * 4;

#pragma unroll
    for (int m = 0; m < 8; ++m) {
#pragma unroll
        for (int q = 0; q < 4; ++q) {
            int row = rbase + m * 16 + q;
            float ib = acc[m][0][q] + b_i;
            float fb = acc[m][1][q] + b_f;
            float ob = acc[m][2][q] + b_o;
            float gb = acc[m][3][q] + b_g;
            float ig = fast_sigmoid(ib);
            float fg = fast_sigmoid(fb);
            float og = fast_sigmoid(ob);
            float gg = fast_tanh(gb);
            float pc = prevc[(size_t)row * SDIM + st];
            float nc = pc * fg + gg * ig;
            float nh = fast_tanh(nc) * og;
            outh[(size_t)row * SDIM + st] = nh;
            outc[(size_t)row * SDIM + st] = nc;
        }
    }
}

extern "C" void kernel_launch(void* const* d_in, const int* in_sizes, int n_in,
                              void* d_out, int out_size, void* d_ws, size_t ws_size,
                              hipStream_t stream) {
    const float* x     = (const float*)d_in[0];
    const float* prevh = (const float*)d_in[1];
    const float* prevc = (const float*)d_in[2];
    const float* Wx    = (const float*)d_in[3];
    const float* bx    = (const float*)d_in[4];
    const float* Wh    = (const float*)d_in[5];

    __hip_bfloat16* Abf = (__hip_bfloat16*)d_ws;
    __hip_bfloat16* Wt  = Abf + (size_t)BATCH * KDIM;   // +32MB

    float* outh = (float*)d_out;
    float* outc = outh + (size_t)BATCH * SDIM;

    hipLaunchKernelGGL(convA, dim3(8192), dim3(256), 0, stream, x, prevh, Abf);
    hipLaunchKernelGGL(convW, dim3(64, 128), dim3(32, 8), 0, stream, Wx, Wh, Wt);
    hipLaunchKernelGGL(lstm_gemm, dim3(512), dim3(512), 0, stream,
                       Abf, Wt, bx, prevc, outh, outc);
}

// Round 10
// 160.487 us; speedup vs baseline: 7.5758x; 7.5758x over previous
//
#include <hip/hip_runtime.h>
#include <hip/hip_bf16.h>

// LSTM cell fused kernel for MI355X (gfx950) — round 10: r3's 8-phase
// schedule + kf-outer INDEPENDENT MFMA ordering (the m201 cell r3 missed).
// stacked = [x|prevh] @ [Wx;Wh] + bx  -> gates -> nexth, nextc
// GEMM: M=8192, N=4096 (4 gates x 1024 states), K=2048, bf16 16x16x32 MFMA.
//
// Structure: 256x256 tile, BK=64, 8 waves (2M x 4N), per-wave 128x64.
// LDS 128 KiB: A ring 4 half-slots [0,64K), B ring [64K,128K);
// half (tile t, p) at slot 2*(t&1)+p.
//
// Per K-tile t, 4 phases; each = {ds_read subtile; stage 1 half; [lgkm(8) if
// 12 reads]; barrier; lgkmcnt(0); setprio(1); 16 MFMA kf-OUTER (8 indep acc
// chains); setprio(0); barrier}:
//   P1: read A[m0-3]x2kf(8) + B[g0-1]x2kf(4); stage A0(t+1); MFMA m0-3 x g0-1
//   P2: read B[g2-3](4);                      stage A1(t+1); MFMA m0-3 x g2-3
//   P3: read A[m4-7](8);                      stage B0(t+2); MFMA m4-7 x g2-3
//   P4: (no reads);                           stage B1(t+2); MFMA m4-7 x g0-1
//       then s_waitcnt vmcnt(4) before trailing barrier.
// vmcnt(4) at P4(t): queue oldest-first ... A0(t+1)[2] A1(t+1)[2] B0(t+2)[2]
// B1(t+2)[2] -> confirms everything tile t+1 reads; 4 stay in flight.
// Ring safety: A0(t+1) overwrites A0(t-1), last read P3(t-1), staged after
// P4(t-1) trailing barrier. B0(t+2) overwrites B0(t), last read P2(t),
// staged at P3(t) after P2's trailing barrier. Safe. (r3-verified)
//
// T2 swizzle both-sides (rule 21; r3-r6 measured 0 bank conflicts):
// 128B rows, granule gl stored at gl ^ (row&7); staging = linear gload_lds
// dest + inverse-swizzled global source col; reads use swz0/swz1.
//
// Gate fusion: Wt pre-permuted n' = (s>>4)*64 + gate*16 + (s&15) so each
// wave's 64 N-cols = 16 states x 4 gates -> epilogue lane-local.
//
// ws layout: A_bf16 [8192][2048] (32MB) | Wt_bf16 [4096 perm][2048] (16MB)

#define BATCH   8192
#define SDIM    1024
#define KDIM    2048
#define NT      32      // K-tiles of 64

typedef __attribute__((ext_vector_type(8))) short s16x8;
typedef __attribute__((ext_vector_type(4))) float f32x4;

__device__ __forceinline__ void gload16(const void* g, void* l) {
    __builtin_amdgcn_global_load_lds((const __attribute__((address_space(1))) void*)g,
                                     (__attribute__((address_space(3))) void*)l,
                                     16, 0, 0);
}

__device__ __forceinline__ float fast_sigmoid(float x) {
    return 1.0f / (1.0f + __expf(-x));
}
__device__ __forceinline__ float fast_tanh(float v) {
    float a = fabsf(v);
    float e = __expf(-2.0f * a);
    float t = (1.0f - e) / (1.0f + e);
    return copysignf(t, v);
}

// ---------------- conversion: A = [x | prevh] -> bf16 [8192][2048] ----------
__global__ void convA(const float* __restrict__ x, const float* __restrict__ h,
                      __hip_bfloat16* __restrict__ A) {
    int t = blockIdx.x * blockDim.x + threadIdx.x;
    int e = t << 3;
    int b = e >> 11;
    int k = e & 2047;
    const float* src = (k < 1024) ? (x + (size_t)b * 1024 + k)
                                  : (h + (size_t)b * 1024 + (k - 1024));
    float4 v0 = *(const float4*)(src);
    float4 v1 = *(const float4*)(src + 4);
    union { __hip_bfloat16 b[8]; s16x8 v; } u;
    u.b[0] = __float2bfloat16(v0.x); u.b[1] = __float2bfloat16(v0.y);
    u.b[2] = __float2bfloat16(v0.z); u.b[3] = __float2bfloat16(v0.w);
    u.b[4] = __float2bfloat16(v1.x); u.b[5] = __float2bfloat16(v1.y);
    u.b[6] = __float2bfloat16(v1.z); u.b[7] = __float2bfloat16(v1.w);
    *(s16x8*)(A + e) = u.v;
}

// ---- conversion + transpose + gate-permute: Wt[n'][k] = W[k][n] -----------
// n = gate*1024 + s  ->  n' = (s>>4)*64 + gate*16 + (s&15)
__global__ void convW(const float* __restrict__ Wx, const float* __restrict__ Wh,
                      __hip_bfloat16* __restrict__ Wt) {
    __shared__ float tile[32][33];
    int k0 = blockIdx.x * 32;
    int n0 = blockIdx.y * 32;
    int tx = threadIdx.x;
    int ty = threadIdx.y;
#pragma unroll
    for (int j = 0; j < 4; ++j) {
        int k = k0 + ty + j * 8;
        int n = n0 + tx;
        float v = (k < 1024) ? Wx[(size_t)k * 4096 + n]
                             : Wh[(size_t)(k - 1024) * 4096 + n];
        tile[ty + j * 8][tx] = v;
    }
    __syncthreads();
#pragma unroll
    for (int j = 0; j < 4; ++j) {
        int n = n0 + ty + j * 8;
        int k = k0 + tx;
        int np = ((n & 1023) >> 4) * 64 + (n >> 10) * 16 + (n & 15);
        Wt[(size_t)np * 2048 + k] = __float2bfloat16(tile[tx][ty + j * 8]);
    }
}

// ---------------- fused GEMM + gates (8-phase, kf-outer MFMA) ---------------
__global__ __launch_bounds__(512, 2) void lstm_gemm(
    const __hip_bfloat16* __restrict__ A,    // [8192][2048]
    const __hip_bfloat16* __restrict__ Wt,   // [4096 perm][2048]
    const float* __restrict__ bx,            // [4096]
    const float* __restrict__ prevc,         // [8192][1024]
    float* __restrict__ outh,
    float* __restrict__ outc)
{
    // A: slots 0..3 at [0, 64K); B: slots at [64K, 128K). Slot = 16KB.
    __shared__ __align__(16) char lds[131072];

    const int tid  = threadIdx.x;
    const int lane = tid & 63;
    const int w    = tid >> 6;   // 0..7
    const int wr   = w >> 2;     // 0..1  A-half
    const int wc   = w & 3;      // 0..3  N quarter; B-half = wc>>1
    const int l15  = lane & 15;

    // XCD chunking: 8 chunks of (8 Mtiles x 8 Ntiles).
    const int bid = blockIdx.x;
    const int xcd = bid & 7, j = bid >> 3;
    const int mt = (xcd >> 1) * 8 + (j & 7);     // 0..31
    const int nt = (xcd & 1) * 8 + (j >> 3);     // 0..15
    const int m0 = mt * 256, n0 = nt * 256, S0 = nt * 64;

    // ---- staging: linear dest, inverse-swizzled source (rule 21) ----
    const int scol = ((lane & 7) ^ (lane >> 3)) << 3;   // elems
    const __hip_bfloat16* Ag = A  + (size_t)m0 * KDIM;
    const __hip_bfloat16* Bg = Wt + (size_t)n0 * KDIM;

    auto SA = [&](int tt, int p) {
        char* dst = lds + (2 * (tt & 1) + p) * 16384 + w * 1024;
        const __hip_bfloat16* src =
            Ag + (size_t)(p * 128 + w * 8 + (lane >> 3)) * KDIM + tt * 64 + scol;
        gload16(src, dst);
        gload16(src + (size_t)64 * KDIM, dst + 8192);
    };
    auto SB = [&](int tt, int p) {
        char* dst = lds + 65536 + (2 * (tt & 1) + p) * 16384 + w * 1024;
        const __hip_bfloat16* src =
            Bg + (size_t)(p * 128 + w * 8 + (lane >> 3)) * KDIM + tt * 64 + scol;
        gload16(src, dst);
        gload16(src + (size_t)64 * KDIM, dst + 8192);
    };

    f32x4 acc[8][4];
#pragma unroll
    for (int m = 0; m < 8; ++m)
#pragma unroll
        for (int g = 0; g < 4; ++g)
            acc[m][g] = (f32x4)0.0f;

    // prologue: B(0),A(0),B(1) = 12 loads; vmcnt(4) leaves SB(1) in flight.
    SB(0, 0); SB(0, 1); SA(0, 0); SA(0, 1); SB(1, 0); SB(1, 1);
    asm volatile("s_waitcnt vmcnt(4)" ::: "memory");
    __builtin_amdgcn_s_barrier();

    // read-side swizzle: granule' = (kf*4 + (lane>>4)) ^ (lane&7), bytes<<4
    const int swz0 = (((lane >> 4))     ^ (lane & 7)) << 4;
    const int swz1 = (((lane >> 4) | 4) ^ (lane & 7)) << 4;
    const int brow = (wc & 1) * 64;

    s16x8 af[4][2], bf[4][2];

#define PH_SYNC()                                           \
    __builtin_amdgcn_s_barrier();                           \
    asm volatile("s_waitcnt lgkmcnt(0)" ::: "memory");      \
    __builtin_amdgcn_sched_barrier(0);                      \
    __builtin_amdgcn_s_setprio(1);

#define PH_END()                                            \
    __builtin_amdgcn_s_setprio(0);                          \
    __builtin_amdgcn_s_barrier();

// kf-OUTER: 8 independent acc chains between dependent reuses.
#define MFMA8(AIDX0, GBASE, ABASE)                                            \
    _Pragma("unroll")                                                         \
    for (int kf = 0; kf < 2; ++kf)                                            \
        _Pragma("unroll")                                                     \
        for (int m = 0; m < 4; ++m)                                           \
            _Pragma("unroll")                                                 \
            for (int g = 0; g < 2; ++g)                                       \
                acc[(ABASE) + m][(GBASE) + g] =                               \
                    __builtin_amdgcn_mfma_f32_16x16x32_bf16(                  \
                        af[m][kf], bf[(GBASE) + g][kf],                       \
                        acc[(ABASE) + m][(GBASE) + g], 0, 0, 0);

    for (int t = 0; t < NT; ++t) {
        const char* as = lds + (2 * (t & 1) + wr) * 16384;
        const char* bs = lds + 65536 + (2 * (t & 1) + (wc >> 1)) * 16384;

        // ---------------- P1: A[m0-3], B[g0-1]; stage A0(t+1) --------------
#pragma unroll
        for (int m = 0; m < 4; ++m) {
            af[m][0] = *(const s16x8*)(as + (m * 16 + l15) * 128 + swz0);
            af[m][1] = *(const s16x8*)(as + (m * 16 + l15) * 128 + swz1);
        }
#pragma unroll
        for (int g = 0; g < 2; ++g) {
            bf[g][0] = *(const s16x8*)(bs + (brow + g * 16 + l15) * 128 + swz0);
            bf[g][1] = *(const s16x8*)(bs + (brow + g * 16 + l15) * 128 + swz1);
        }
        if (t + 1 < NT) SA(t + 1, 0);
        asm volatile("s_waitcnt lgkmcnt(8)" ::: "memory");   // m201: cap at 8
        PH_SYNC();
        MFMA8(0, 0, 0);
        PH_END();

        // ---------------- P2: B[g2-3]; stage A1(t+1) -----------------------
#pragma unroll
        for (int g = 2; g < 4; ++g) {
            bf[g][0] = *(const s16x8*)(bs + (brow + g * 16 + l15) * 128 + swz0);
            bf[g][1] = *(const s16x8*)(bs + (brow + g * 16 + l15) * 128 + swz1);
        }
        if (t + 1 < NT) SA(t + 1, 1);
        PH_SYNC();
        MFMA8(0, 2, 0);
        PH_END();

        // ---------------- P3: A[m4-7]; stage B0(t+2) -----------------------
#pragma unroll
        for (int m = 0; m < 4; ++m) {
            af[m][0] = *(const s16x8*)(as + ((m + 4) * 16 + l15) * 128 + swz0);
            af[m][1] = *(const s16x8*)(as + ((m + 4) * 16 + l15) * 128 + swz1);
        }
        if (t + 2 < NT) SB(t + 2, 0);
        PH_SYNC();
        MFMA8(0, 2, 4);
        PH_END();

        // ---------------- P4: stage B1(t+2); counted vmcnt -----------------
        if (t + 2 < NT) SB(t + 2, 1);
        __builtin_amdgcn_s_barrier();
        __builtin_amdgcn_s_setprio(1);
        MFMA8(0, 0, 4);
        __builtin_amdgcn_s_setprio(0);
        if (t + 2 < NT) {
            asm volatile("s_waitcnt vmcnt(4)" ::: "memory");
        } else {
            asm volatile("s_waitcnt vmcnt(0)" ::: "memory");
        }
        __builtin_amdgcn_s_barrier();
    }
#undef PH_SYNC
#undef PH_END
#undef MFMA8

    // ---- fused epilogue: 4 gates lane-local ----
    const int st  = S0 + wc * 16 + l15;
    const float b_i = bx[st];
    const float b_f = bx[1024 + st];
    const float b_o = bx[2048 + st];
    const float b_g = bx[3072 + st];
    const int rbase = m0 + wr * 128 + (lane >> 4) * 4;

#pragma unroll
    for (int m = 0; m < 8; ++m) {
#pragma unroll
        for (int q = 0; q < 4; ++q) {
            int row = rbase + m * 16 + q;
            float ib = acc[m][0][q] + b_i;
            float fb = acc[m][1][q] + b_f;
            float ob = acc[m][2][q] + b_o;
            float gb = acc[m][3][q] + b_g;
            float ig = fast_sigmoid(ib);
            float fg = fast_sigmoid(fb);
            float og = fast_sigmoid(ob);
            float gg = fast_tanh(gb);
            float pc = prevc[(size_t)row * SDIM + st];
            float nc = pc * fg + gg * ig;
            float nh = fast_tanh(nc) * og;
            outh[(size_t)row * SDIM + st] = nh;
            outc[(size_t)row * SDIM + st] = nc;
        }
    }
}

extern "C" void kernel_launch(void* const* d_in, const int* in_sizes, int n_in,
                              void* d_out, int out_size, void* d_ws, size_t ws_size,
                              hipStream_t stream) {
    const float* x     = (const float*)d_in[0];
    const float* prevh = (const float*)d_in[1];
    const float* prevc = (const float*)d_in[2];
    const float* Wx    = (const float*)d_in[3];
    const float* bx    = (const float*)d_in[4];
    const float* Wh    = (const float*)d_in[5];

    __hip_bfloat16* Abf = (__hip_bfloat16*)d_ws;
    __hip_bfloat16* Wt  = Abf + (size_t)BATCH * KDIM;   // +32MB

    float* outh = (float*)d_out;
    float* outc = outh + (size_t)BATCH * SDIM;

    hipLaunchKernelGGL(convA, dim3(8192), dim3(256), 0, stream, x, prevh, Abf);
    hipLaunchKernelGGL(convW, dim3(64, 128), dim3(32, 8), 0, stream, Wx, Wh, Wt);
    hipLaunchKernelGGL(lstm_gemm, dim3(512), dim3(512), 0, stream,
                       Abf, Wt, bx, prevc, outh, outc);
}

// Round 11
// 156.338 us; speedup vs baseline: 7.7768x; 1.0265x over previous
//
#include <hip/hip_runtime.h>
#include <hip/hip_bf16.h>

// LSTM cell fused kernel for MI355X (gfx950) — round 11:
// gemm = round-4 verbatim (best measured: 156.36 µs total);
// conversions merged into ONE kernel (convAW) with vectorized W stores.
//
// stacked = [x|prevh] @ [Wx;Wh] + bx -> gates -> nexth, nextc
// GEMM: M=8192, N=4096 (4 gates x 1024 states), K=2048, bf16 16x16x32 MFMA.
//
// ws layout: A_bf16 [8192][2048] (32MB) | Wt_bf16 [4096 perm][2048] (16MB)

#define BATCH   8192
#define SDIM    1024
#define KDIM    2048
#define NT      32      // K-tiles of 64

typedef __attribute__((ext_vector_type(8))) short s16x8;
typedef __attribute__((ext_vector_type(4))) float f32x4;

__device__ __forceinline__ void gload16(const void* g, void* l) {
    __builtin_amdgcn_global_load_lds((const __attribute__((address_space(1))) void*)g,
                                     (__attribute__((address_space(3))) void*)l,
                                     16, 0, 0);
}

__device__ __forceinline__ float fast_sigmoid(float x) {
    return 1.0f / (1.0f + __expf(-x));
}
__device__ __forceinline__ float fast_tanh(float v) {
    float a = fabsf(v);
    float e = __expf(-2.0f * a);
    float t = (1.0f - e) / (1.0f + e);
    return copysignf(t, v);
}

// ---------------- merged conversions ----------------------------------------
// blocks [0, 8192):  A = [x | prevh] -> bf16 [8192][2048]   (16B loads/stores)
// blocks [8192, 10240): Wt[np][k] = W[k][n], np = (s>>4)*64 + g*16 + (s&15)
//   via 64k x 64n LDS transpose tile; 16B (8-k-run) stores.
__global__ __launch_bounds__(256) void convAW(
    const float* __restrict__ x,  const float* __restrict__ h,
    const float* __restrict__ Wx, const float* __restrict__ Wh,
    __hip_bfloat16* __restrict__ A, __hip_bfloat16* __restrict__ Wt)
{
    __shared__ float tile[64][68];   // row base = r*272B (16B-aligned); banks 2-way max
    if (blockIdx.x < 8192) {
        int t = blockIdx.x * 256 + threadIdx.x;
        int e = t << 3;
        int b = e >> 11;
        int k = e & 2047;
        const float* src = (k < 1024) ? (x + (size_t)b * 1024 + k)
                                      : (h + (size_t)b * 1024 + (k - 1024));
        float4 v0 = *(const float4*)(src);
        float4 v1 = *(const float4*)(src + 4);
        union { __hip_bfloat16 b[8]; s16x8 v; } u;
        u.b[0] = __float2bfloat16(v0.x); u.b[1] = __float2bfloat16(v0.y);
        u.b[2] = __float2bfloat16(v0.z); u.b[3] = __float2bfloat16(v0.w);
        u.b[4] = __float2bfloat16(v1.x); u.b[5] = __float2bfloat16(v1.y);
        u.b[6] = __float2bfloat16(v1.z); u.b[7] = __float2bfloat16(v1.w);
        *(s16x8*)(A + e) = u.v;
    } else {
        const int wb = blockIdx.x - 8192;   // 0..2047
        const int kt = wb & 31;             // 32 k-tiles of 64
        const int nt = wb >> 5;             // 64 n-tiles of 64
        const int k0 = kt * 64, n0 = nt * 64;
        const int t  = threadIdx.x;

        // load: 4 threads per k-row, 16 n each (4 x float4), coalesced
        {
            int r = t >> 2;
            int c = (t & 3) * 16;
            int k = k0 + r;   // k0 is 64-aligned: row never straddles Wx/Wh
            const float* src = (k < 1024) ? (Wx + (size_t)k * 4096 + n0 + c)
                                          : (Wh + (size_t)(k - 1024) * 4096 + n0 + c);
#pragma unroll
            for (int jq = 0; jq < 4; ++jq)
                *(float4*)&tile[r][c + jq * 4] = *(const float4*)(src + jq * 4);
        }
        __syncthreads();

        // store: item = oct*64 + n_local; per item one 16B (8-k) store
#pragma unroll
        for (int it = 0; it < 2; ++it) {
            int item = t + it * 256;
            int oct  = item >> 6;          // 0..7
            int nl   = item & 63;
            int n    = n0 + nl;
            int s    = n & 1023, g = n >> 10;
            int np   = (s >> 4) * 64 + g * 16 + (s & 15);
            union { __hip_bfloat16 b[8]; s16x8 v; } u;
#pragma unroll
            for (int e = 0; e < 8; ++e)
                u.b[e] = __float2bfloat16(tile[oct * 8 + e][nl]);
            *(s16x8*)(Wt + (size_t)np * 2048 + k0 + oct * 8) = u.v;
        }
    }
}

// ---------------- fused GEMM + gates (round-4 verbatim) ---------------------
// 256x256 tile, BK=64, 8 waves (2M x 4N); A ring 4 half-slots [0,64K),
// B ring [64K,128K), half (t,p) at slot 2*(t&1)+p. 2 barriers/tile:
//   region1: bf reads(8) + af-lo reads(8) + SA(t+1)x2; 32 MFMA kf-outer
//   mid-barrier (B(t) LDS reads retired)
//   region2: af-hi reads(8, reuse regs) + SB(t+2)x2; 32 MFMA; vmcnt(4); bar
// T2 swizzle both-sides (0 conflicts measured r3-r6), XCD chunking,
// gate-permuted Wt -> lane-local epilogue.
__global__ __launch_bounds__(512, 2) void lstm_gemm(
    const __hip_bfloat16* __restrict__ A,    // [8192][2048]
    const __hip_bfloat16* __restrict__ Wt,   // [4096 perm][2048]
    const float* __restrict__ bx,            // [4096]
    const float* __restrict__ prevc,         // [8192][1024]
    float* __restrict__ outh,
    float* __restrict__ outc)
{
    __shared__ __align__(16) char lds[131072];

    const int tid  = threadIdx.x;
    const int lane = tid & 63;
    const int w    = tid >> 6;   // 0..7
    const int wr   = w >> 2;     // 0..1  A-half
    const int wc   = w & 3;      // 0..3  N quarter; B-half = wc>>1
    const int l15  = lane & 15;

    const int bid = blockIdx.x;
    const int xcd = bid & 7, j = bid >> 3;
    const int mt = (xcd >> 1) * 8 + (j & 7);     // 0..31
    const int nt = (xcd & 1) * 8 + (j >> 3);     // 0..15
    const int m0 = mt * 256, n0 = nt * 256, S0 = nt * 64;

    const int scol = ((lane & 7) ^ (lane >> 3)) << 3;   // elems
    const __hip_bfloat16* Ag = A  + (size_t)m0 * KDIM;
    const __hip_bfloat16* Bg = Wt + (size_t)n0 * KDIM;

    auto SA = [&](int tt, int p) {
        char* dst = lds + (2 * (tt & 1) + p) * 16384 + w * 1024;
        const __hip_bfloat16* src =
            Ag + (size_t)(p * 128 + w * 8 + (lane >> 3)) * KDIM + tt * 64 + scol;
        gload16(src, dst);
        gload16(src + (size_t)64 * KDIM, dst + 8192);
    };
    auto SB = [&](int tt, int p) {
        char* dst = lds + 65536 + (2 * (tt & 1) + p) * 16384 + w * 1024;
        const __hip_bfloat16* src =
            Bg + (size_t)(p * 128 + w * 8 + (lane >> 3)) * KDIM + tt * 64 + scol;
        gload16(src, dst);
        gload16(src + (size_t)64 * KDIM, dst + 8192);
    };

    f32x4 acc[8][4];
#pragma unroll
    for (int m = 0; m < 8; ++m)
#pragma unroll
        for (int g = 0; g < 4; ++g)
            acc[m][g] = (f32x4)0.0f;

    SB(0, 0); SB(0, 1); SA(0, 0); SA(0, 1); SB(1, 0); SB(1, 1);
    asm volatile("s_waitcnt vmcnt(4)" ::: "memory");
    __builtin_amdgcn_s_barrier();
    __builtin_amdgcn_sched_barrier(0);

    const int swz0 = (((lane >> 4))     ^ (lane & 7)) << 4;
    const int swz1 = (((lane >> 4) | 4) ^ (lane & 7)) << 4;
    const int brow = (wc & 1) * 64;

    s16x8 af[4][2], bf[4][2];

    for (int t = 0; t < NT; ++t) {
        const char* as = lds + (2 * (t & 1) + wr) * 16384;
        const char* bs = lds + 65536 + (2 * (t & 1) + (wc >> 1)) * 16384;

        // ---- region 1: B reads, A-lo reads, SA(t+1); MFMA m0-3 x g0-3 ----
#pragma unroll
        for (int g = 0; g < 4; ++g) {
            bf[g][0] = *(const s16x8*)(bs + (brow + g * 16 + l15) * 128 + swz0);
            bf[g][1] = *(const s16x8*)(bs + (brow + g * 16 + l15) * 128 + swz1);
        }
#pragma unroll
        for (int m = 0; m < 4; ++m) {
            af[m][0] = *(const s16x8*)(as + (m * 16 + l15) * 128 + swz0);
            af[m][1] = *(const s16x8*)(as + (m * 16 + l15) * 128 + swz1);
        }
        if (t + 1 < NT) { SA(t + 1, 0); SA(t + 1, 1); }

        __builtin_amdgcn_s_setprio(1);
#pragma unroll
        for (int kf = 0; kf < 2; ++kf)
#pragma unroll
            for (int m = 0; m < 4; ++m)
#pragma unroll
                for (int g = 0; g < 4; ++g)
                    acc[m][g] = __builtin_amdgcn_mfma_f32_16x16x32_bf16(
                        af[m][kf], bf[g][kf], acc[m][g], 0, 0, 0);
        __builtin_amdgcn_s_setprio(0);

        __builtin_amdgcn_sched_barrier(0);
        __builtin_amdgcn_s_barrier();        // mid: all B(t) reads retired
        __builtin_amdgcn_sched_barrier(0);

        // ---- region 2: A-hi reads (reuse af), SB(t+2); MFMA m4-7 x g0-3 ----
#pragma unroll
        for (int m = 0; m < 4; ++m) {
            af[m][0] = *(const s16x8*)(as + ((m + 4) * 16 + l15) * 128 + swz0);
            af[m][1] = *(const s16x8*)(as + ((m + 4) * 16 + l15) * 128 + swz1);
        }
        if (t + 2 < NT) { SB(t + 2, 0); SB(t + 2, 1); }

        __builtin_amdgcn_s_setprio(1);
#pragma unroll
        for (int kf = 0; kf < 2; ++kf)
#pragma unroll
            for (int m = 0; m < 4; ++m)
#pragma unroll
                for (int g = 0; g < 4; ++g)
                    acc[m + 4][g] = __builtin_amdgcn_mfma_f32_16x16x32_bf16(
                        af[m][kf], bf[g][kf], acc[m + 4][g], 0, 0, 0);
        __builtin_amdgcn_s_setprio(0);

        __builtin_amdgcn_sched_barrier(0);
        if (t + 2 < NT) {
            asm volatile("s_waitcnt vmcnt(4)" ::: "memory");
        } else {
            asm volatile("s_waitcnt vmcnt(0)" ::: "memory");
        }
        __builtin_amdgcn_s_barrier();        // end: tile t+1 slots published
        __builtin_amdgcn_sched_barrier(0);
    }

    // ---- fused epilogue: 4 gates lane-local ----
    const int st  = S0 + wc * 16 + l15;
    const float b_i = bx[st];
    const float b_f = bx[1024 + st];
    const float b_o = bx[2048 + st];
    const float b_g = bx[3072 + st];
    const int rbase = m0 + wr * 128 + (lane >> 4) * 4;

#pragma unroll
    for (int m = 0; m < 8; ++m) {
#pragma unroll
        for (int q = 0; q < 4; ++q) {
            int row = rbase + m * 16 + q;
            float ib = acc[m][0][q] + b_i;
            float fb = acc[m][1][q] + b_f;
            float ob = acc[m][2][q] + b_o;
            float gb = acc[m][3][q] + b_g;
            float ig = fast_sigmoid(ib);
            float fg = fast_sigmoid(fb);
            float og = fast_sigmoid(ob);
            float gg = fast_tanh(gb);
            float pc = prevc[(size_t)row * SDIM + st];
            float nc = pc * fg + gg * ig;
            float nh = fast_tanh(nc) * og;
            outh[(size_t)row * SDIM + st] = nh;
            outc[(size_t)row * SDIM + st] = nc;
        }
    }
}

extern "C" void kernel_launch(void* const* d_in, const int* in_sizes, int n_in,
                              void* d_out, int out_size, void* d_ws, size_t ws_size,
                              hipStream_t stream) {
    const float* x     = (const float*)d_in[0];
    const float* prevh = (const float*)d_in[1];
    const float* prevc = (const float*)d_in[2];
    const float* Wx    = (const float*)d_in[3];
    const float* bx    = (const float*)d_in[4];
    const float* Wh    = (const float*)d_in[5];

    __hip_bfloat16* Abf = (__hip_bfloat16*)d_ws;
    __hip_bfloat16* Wt  = Abf + (size_t)BATCH * KDIM;   // +32MB

    float* outh = (float*)d_out;
    float* outc = outh + (size_t)BATCH * SDIM;

    // merged conversions: 8192 A-blocks + 2048 W-blocks
    hipLaunchKernelGGL(convAW, dim3(10240), dim3(256), 0, stream,
                       x, prevh, Wx, Wh, Abf, Wt);
    hipLaunchKernelGGL(lstm_gemm, dim3(512), dim3(512), 0, stream,
                       Abf, Wt, bx, prevc, outh, outc);
}